// Round 1
// baseline (10625.802 us; speedup 1.0000x reference)
//
#include <hip/hip_runtime.h>

// Problem constants (match reference setup_inputs)
constexpr int NN = 100000;   // nodes
constexpr int NE = 1600000;  // edges
constexpr int NG = 128;      // graphs

// ---------------- kernels ----------------

__global__ void k_deg(const int* __restrict__ dst, const float* __restrict__ w,
                      float* __restrict__ deg, int ne) {
    int e = blockIdx.x * blockDim.x + threadIdx.x;
    if (e < ne) atomicAdd(&deg[dst[e]], w[e]);
}

__global__ void k_dinv(float* __restrict__ deg, int nn) {
    int i = blockIdx.x * blockDim.x + threadIdx.x;
    if (i < nn) {
        float d = deg[i];
        deg[i] = d > 0.f ? rsqrtf(fmaxf(d, 1e-30f)) : 0.f;
    }
}

__global__ void k_norm(const int* __restrict__ src, const int* __restrict__ dst,
                       const float* __restrict__ w, const float* __restrict__ dinv,
                       float* __restrict__ norm, int ne) {
    int e = blockIdx.x * blockDim.x + threadIdx.x;
    if (e < ne) norm[e] = dinv[src[e]] * w[e] * dinv[dst[e]];
}

// scatter-add propagate: hout[dst] += hin[src] * norm   (hout must be zeroed)
template <int F>
__global__ void k_prop(const int* __restrict__ src, const int* __restrict__ dst,
                       const float* __restrict__ norm,
                       const float* __restrict__ hin, float* __restrict__ hout, int ne) {
    int e = blockIdx.x * blockDim.x + threadIdx.x;
    if (e >= ne) return;
    int s = src[e], d = dst[e];
    float nm = norm[e];
    const float4* hs = reinterpret_cast<const float4*>(hin + (size_t)s * F);
    float* hd = hout + (size_t)d * F;
#pragma unroll
    for (int f = 0; f < F / 4; ++f) {
        float4 v = hs[f];
        atomicAdd(hd + 4 * f + 0, v.x * nm);
        atomicAdd(hd + 4 * f + 1, v.y * nm);
        atomicAdd(hd + 4 * f + 2, v.z * nm);
        atomicAdd(hd + 4 * f + 3, v.w * nm);
    }
}

// out[n][:] (+)= h[n][:] @ W   (W row-major FIN x FOUT, staged in LDS)
template <int FIN, int FOUT, bool ACC>
__global__ void k_mm(const float* __restrict__ h, const float* __restrict__ W,
                     float* __restrict__ out, int nn) {
    __shared__ float sW[FIN * FOUT];
    for (int i = threadIdx.x; i < FIN * FOUT; i += blockDim.x) sW[i] = W[i];
    __syncthreads();
    int n = blockIdx.x * blockDim.x + threadIdx.x;
    if (n >= nn) return;
    float hr[FIN];
    const float4* hp = reinterpret_cast<const float4*>(h + (size_t)n * FIN);
#pragma unroll
    for (int f = 0; f < FIN / 4; ++f) {
        float4 v = hp[f];
        hr[4 * f + 0] = v.x; hr[4 * f + 1] = v.y;
        hr[4 * f + 2] = v.z; hr[4 * f + 3] = v.w;
    }
#pragma unroll
    for (int j = 0; j < FOUT; ++j) {
        float acc = 0.f;
#pragma unroll
        for (int i = 0; i < FIN; ++i) acc += hr[i] * sW[i * FOUT + j];
        if (ACC) out[(size_t)n * FOUT + j] += acc;
        else     out[(size_t)n * FOUT + j] = acc;
    }
}

template <int F>
__global__ void k_bias_relu(float* __restrict__ h, const float* __restrict__ b, int nn) {
    int idx = blockIdx.x * blockDim.x + threadIdx.x;
    if (idx < nn * F) {
        int j = idx & (F - 1);  // F is a power of two
        h[idx] = fmaxf(h[idx] + b[j], 0.f);
    }
}

// global max + sum pool (values are >= 0 post-ReLU, so int-bits atomicMax is valid)
__global__ void k_pool(const float* __restrict__ h, const int* __restrict__ batch,
                       float* __restrict__ mx, float* __restrict__ sm,
                       float* __restrict__ cnt, int nn) {
    int n = blockIdx.x * blockDim.x + threadIdx.x;
    if (n >= nn) return;
    int g = batch[n];
    const float* hr = h + (size_t)n * 16;
#pragma unroll
    for (int j = 0; j < 16; ++j) {
        float v = hr[j];
        atomicMax(reinterpret_cast<int*>(&mx[g * 16 + j]), __float_as_int(v));
        atomicAdd(&sm[g * 16 + j], v);
    }
    atomicAdd(&cnt[g], 1.0f);
}

__global__ void k_final(const float* __restrict__ mx, const float* __restrict__ sm,
                        const float* __restrict__ cnt, const float* __restrict__ Wfc,
                        const float* __restrict__ bfc, float* __restrict__ out) {
    int idx = blockIdx.x * blockDim.x + threadIdx.x;
    if (idx >= NG * 2) return;
    int g = idx >> 1, c = idx & 1;
    float inv = 1.0f / fmaxf(cnt[g], 1.0f);
    float acc = bfc[c];
#pragma unroll
    for (int i = 0; i < 16; ++i) acc += mx[g * 16 + i] * Wfc[i * 2 + c];
#pragma unroll
    for (int i = 0; i < 16; ++i) acc += sm[g * 16 + i] * inv * Wfc[(16 + i) * 2 + c];
    out[idx] = acc;
}

// ---------------- launch ----------------

extern "C" void kernel_launch(void* const* d_in, const int* in_sizes, int n_in,
                              void* d_out, int out_size, void* d_ws, size_t ws_size,
                              hipStream_t stream) {
    const float* x    = (const float*)d_in[0];           // NN x 32
    const int*   eidx = (const int*)d_in[1];             // 2 x NE
    const int*   srcp = eidx;
    const int*   dstp = eidx + NE;
    const int*   batch= (const int*)d_in[2];             // NN
    const float* ew   = (const float*)d_in[3];           // NE
    const float* W1   = (const float*)d_in[4];           // 4 x 32 x 8
    const float* b1   = (const float*)d_in[5];           // 8
    const float* W2   = (const float*)d_in[6];           // 4 x 8 x 16
    const float* b2   = (const float*)d_in[7];           // 16
    const float* Wfc  = (const float*)d_in[8];           // 32 x 2
    const float* bfc  = (const float*)d_in[9];           // 2
    float* out = (float*)d_out;                          // NG x 2

    // workspace layout (floats)
    float* F0   = (float*)d_ws;
    float* deg  = F0;                    // NN   (becomes dinv in place)
    float* norm = deg  + NN;             // NE
    float* bufA = norm + NE;             // NN*32
    float* bufB = bufA + (size_t)NN*32;  // NN*32
    float* out1 = bufB + (size_t)NN*32;  // NN*8  (becomes h1)
    float* out2 = out1 + (size_t)NN*8;   // NN*16 (becomes h2)
    float* mx   = out2 + (size_t)NN*16;  // NG*16
    float* sm   = mx   + NG*16;          // NG*16
    float* cnt  = sm   + NG*16;          // NG

    const int BLK = 256;
    const int gE = (NE + BLK - 1) / BLK;
    const int gN = (NN + BLK - 1) / BLK;

    // ---- gcn_norm ----
    hipMemsetAsync(deg, 0, (size_t)NN * sizeof(float), stream);
    k_deg<<<gE, BLK, 0, stream>>>(dstp, ew, deg, NE);
    k_dinv<<<gN, BLK, 0, stream>>>(deg, NN);
    k_norm<<<gE, BLK, 0, stream>>>(srcp, dstp, ew, deg, norm, NE);

    // ---- layer 1: 32 -> 8, K=3 ----
    k_mm<32, 8, false><<<gN, BLK, 0, stream>>>(x, W1 + 0 * 256, out1, NN);

    hipMemsetAsync(bufA, 0, (size_t)NN * 32 * sizeof(float), stream);
    k_prop<32><<<gE, BLK, 0, stream>>>(srcp, dstp, norm, x, bufA, NE);
    k_mm<32, 8, true><<<gN, BLK, 0, stream>>>(bufA, W1 + 1 * 256, out1, NN);

    hipMemsetAsync(bufB, 0, (size_t)NN * 32 * sizeof(float), stream);
    k_prop<32><<<gE, BLK, 0, stream>>>(srcp, dstp, norm, bufA, bufB, NE);
    k_mm<32, 8, true><<<gN, BLK, 0, stream>>>(bufB, W1 + 2 * 256, out1, NN);

    hipMemsetAsync(bufA, 0, (size_t)NN * 32 * sizeof(float), stream);
    k_prop<32><<<gE, BLK, 0, stream>>>(srcp, dstp, norm, bufB, bufA, NE);
    k_mm<32, 8, true><<<gN, BLK, 0, stream>>>(bufA, W1 + 3 * 256, out1, NN);

    k_bias_relu<8><<<(NN * 8 + BLK - 1) / BLK, BLK, 0, stream>>>(out1, b1, NN);

    // ---- layer 2: 8 -> 16, K=3 ----
    k_mm<8, 16, false><<<gN, BLK, 0, stream>>>(out1, W2 + 0 * 128, out2, NN);

    hipMemsetAsync(bufA, 0, (size_t)NN * 8 * sizeof(float), stream);
    k_prop<8><<<gE, BLK, 0, stream>>>(srcp, dstp, norm, out1, bufA, NE);
    k_mm<8, 16, true><<<gN, BLK, 0, stream>>>(bufA, W2 + 1 * 128, out2, NN);

    hipMemsetAsync(bufB, 0, (size_t)NN * 8 * sizeof(float), stream);
    k_prop<8><<<gE, BLK, 0, stream>>>(srcp, dstp, norm, bufA, bufB, NE);
    k_mm<8, 16, true><<<gN, BLK, 0, stream>>>(bufB, W2 + 2 * 128, out2, NN);

    hipMemsetAsync(bufA, 0, (size_t)NN * 8 * sizeof(float), stream);
    k_prop<8><<<gE, BLK, 0, stream>>>(srcp, dstp, norm, bufB, bufA, NE);
    k_mm<8, 16, true><<<gN, BLK, 0, stream>>>(bufA, W2 + 3 * 128, out2, NN);

    k_bias_relu<16><<<(NN * 16 + BLK - 1) / BLK, BLK, 0, stream>>>(out2, b2, NN);

    // ---- pooling + FC ----
    hipMemsetAsync(mx, 0, (size_t)(NG * 16 * 2 + NG) * sizeof(float), stream);
    k_pool<<<gN, BLK, 0, stream>>>(out2, batch, mx, sm, cnt, NN);
    k_final<<<1, 256, 0, stream>>>(mx, sm, cnt, Wfc, bfc, out);
}

// Round 2
// 1386.443 us; speedup vs baseline: 7.6641x; 7.6641x over previous
//
#include <hip/hip_runtime.h>

// Problem constants (match reference setup_inputs)
constexpr int NN = 100000;   // nodes
constexpr int NE = 1600000;  // edges
constexpr int NG = 128;      // graphs

// ---------------- CSR build ----------------

// fused: weighted degree (float) + in-edge count (int)
__global__ void k_deg_cnt(const int* __restrict__ dst, const float* __restrict__ w,
                          float* __restrict__ deg, int* __restrict__ cnt, int ne) {
    int e = blockIdx.x * blockDim.x + threadIdx.x;
    if (e < ne) {
        int d = dst[e];
        atomicAdd(&deg[d], w[e]);
        atomicAdd(&cnt[d], 1);
    }
}

__global__ void k_dinv(float* __restrict__ deg, int nn) {
    int i = blockIdx.x * blockDim.x + threadIdx.x;
    if (i < nn) {
        float d = deg[i];
        deg[i] = d > 0.f ? rsqrtf(fmaxf(d, 1e-30f)) : 0.f;
    }
}

// single-block exclusive scan of cnt -> row_ptr (and cursor copy)
__global__ void k_scan(const int* __restrict__ cnt, int* __restrict__ row_ptr,
                       int* __restrict__ cursor, int nn) {
    constexpr int T = 1024;
    __shared__ int ps[T];
    int t = threadIdx.x;
    int chunk = (nn + T - 1) / T;
    int beg = t * chunk;
    int end = min(beg + chunk, nn);
    int s = 0;
    for (int i = beg; i < end; ++i) s += cnt[i];
    ps[t] = s;
    __syncthreads();
    for (int off = 1; off < T; off <<= 1) {
        int v = (t >= off) ? ps[t - off] : 0;
        __syncthreads();
        ps[t] += v;
        __syncthreads();
    }
    int run = (t > 0) ? ps[t - 1] : 0;
    for (int i = beg; i < end; ++i) {
        row_ptr[i] = run;
        cursor[i] = run;
        run += cnt[i];
    }
    if (t == T - 1) row_ptr[nn] = ps[T - 1];
}

// scatter edges into CSR slots; norm computed inline
__global__ void k_scatter(const int* __restrict__ src, const int* __restrict__ dst,
                          const float* __restrict__ w, const float* __restrict__ dinv,
                          int* __restrict__ cursor, int* __restrict__ csr_src,
                          float* __restrict__ csr_norm, int ne) {
    int e = blockIdx.x * blockDim.x + threadIdx.x;
    if (e >= ne) return;
    int s = src[e], d = dst[e];
    int slot = atomicAdd(&cursor[d], 1);
    csr_src[slot] = s;
    csr_norm[slot] = dinv[s] * w[e] * dinv[d];
}

// ---------------- pull propagate ----------------
// one group of F lanes per node; lane j accumulates feature j
template <int F>
__global__ void k_pull(const int* __restrict__ row_ptr, const int* __restrict__ csr_src,
                       const float* __restrict__ csr_norm,
                       const float* __restrict__ hin, float* __restrict__ hout, int nn) {
    int g = blockIdx.x * (blockDim.x / F) + threadIdx.x / F;
    int lane = threadIdx.x & (F - 1);
    if (g >= nn) return;
    int beg = row_ptr[g], end = row_ptr[g + 1];
    float acc0 = 0.f, acc1 = 0.f;
    int e = beg;
    for (; e + 1 < end; e += 2) {
        int s0 = csr_src[e], s1 = csr_src[e + 1];
        float n0 = csr_norm[e], n1 = csr_norm[e + 1];
        acc0 = fmaf(hin[(size_t)s0 * F + lane], n0, acc0);
        acc1 = fmaf(hin[(size_t)s1 * F + lane], n1, acc1);
    }
    if (e < end) {
        int s0 = csr_src[e];
        acc0 = fmaf(hin[(size_t)s0 * F + lane], csr_norm[e], acc0);
    }
    hout[(size_t)g * F + lane] = acc0 + acc1;
}

// ---------------- dense mm (+ optional fused bias/relu) ----------------
template <int FIN, int FOUT, bool ACC, bool EPI>
__global__ void k_mm(const float* __restrict__ h, const float* __restrict__ W,
                     const float* __restrict__ b, float* __restrict__ out, int nn) {
    __shared__ float sW[FIN * FOUT];
    for (int i = threadIdx.x; i < FIN * FOUT; i += blockDim.x) sW[i] = W[i];
    __syncthreads();
    int n = blockIdx.x * blockDim.x + threadIdx.x;
    if (n >= nn) return;
    float hr[FIN];
    const float4* hp = reinterpret_cast<const float4*>(h + (size_t)n * FIN);
#pragma unroll
    for (int f = 0; f < FIN / 4; ++f) {
        float4 v = hp[f];
        hr[4 * f + 0] = v.x; hr[4 * f + 1] = v.y;
        hr[4 * f + 2] = v.z; hr[4 * f + 3] = v.w;
    }
#pragma unroll
    for (int j = 0; j < FOUT; ++j) {
        float acc = 0.f;
#pragma unroll
        for (int i = 0; i < FIN; ++i) acc += hr[i] * sW[i * FOUT + j];
        size_t o = (size_t)n * FOUT + j;
        float r = ACC ? out[o] + acc : acc;
        if (EPI) r = fmaxf(r + b[j], 0.f);
        out[o] = r;
    }
}

// ---------------- pooling + FC ----------------
__global__ void k_pool(const float* __restrict__ h, const int* __restrict__ batch,
                       float* __restrict__ mx, float* __restrict__ sm,
                       float* __restrict__ cnt, int nn) {
    int n = blockIdx.x * blockDim.x + threadIdx.x;
    if (n >= nn) return;
    int g = batch[n];
    const float* hr = h + (size_t)n * 16;
#pragma unroll
    for (int j = 0; j < 16; ++j) {
        float v = hr[j];
        atomicMax(reinterpret_cast<int*>(&mx[g * 16 + j]), __float_as_int(v));
        atomicAdd(&sm[g * 16 + j], v);
    }
    atomicAdd(&cnt[g], 1.0f);
}

__global__ void k_final(const float* __restrict__ mx, const float* __restrict__ sm,
                        const float* __restrict__ cnt, const float* __restrict__ Wfc,
                        const float* __restrict__ bfc, float* __restrict__ out) {
    int idx = blockIdx.x * blockDim.x + threadIdx.x;
    if (idx >= NG * 2) return;
    int g = idx >> 1, c = idx & 1;
    float inv = 1.0f / fmaxf(cnt[g], 1.0f);
    float acc = bfc[c];
#pragma unroll
    for (int i = 0; i < 16; ++i) acc += mx[g * 16 + i] * Wfc[i * 2 + c];
#pragma unroll
    for (int i = 0; i < 16; ++i) acc += sm[g * 16 + i] * inv * Wfc[(16 + i) * 2 + c];
    out[idx] = acc;
}

// ---------------- launch ----------------

extern "C" void kernel_launch(void* const* d_in, const int* in_sizes, int n_in,
                              void* d_out, int out_size, void* d_ws, size_t ws_size,
                              hipStream_t stream) {
    const float* x    = (const float*)d_in[0];           // NN x 32
    const int*   eidx = (const int*)d_in[1];             // 2 x NE
    const int*   srcp = eidx;
    const int*   dstp = eidx + NE;
    const int*   batch= (const int*)d_in[2];             // NN
    const float* ew   = (const float*)d_in[3];           // NE
    const float* W1   = (const float*)d_in[4];           // 4 x 32 x 8
    const float* b1   = (const float*)d_in[5];           // 8
    const float* W2   = (const float*)d_in[6];           // 4 x 8 x 16
    const float* b2   = (const float*)d_in[7];           // 16
    const float* Wfc  = (const float*)d_in[8];           // 32 x 2
    const float* bfc  = (const float*)d_in[9];           // 2
    float* out = (float*)d_out;                          // NG x 2

    // workspace layout (4-byte units; every block padded to 16B alignment)
    float* deg      = (float*)d_ws;              // NN
    int*   cnt      = (int*)(deg + NN);          // NN
    int*   row_ptr  = cnt + NN;                  // NN + 4 (pad)
    int*   cursor   = row_ptr + NN + 4;          // NN
    int*   csr_src  = cursor + NN;               // NE
    float* csr_norm = (float*)(csr_src + NE);    // NE
    float* bufA     = csr_norm + NE;             // NN*32
    float* bufB     = bufA + (size_t)NN * 32;    // NN*32
    float* out1     = bufB + (size_t)NN * 32;    // NN*8
    float* out2     = out1 + (size_t)NN * 8;     // NN*16
    float* mx       = out2 + (size_t)NN * 16;    // NG*16
    float* sm       = mx + NG * 16;              // NG*16
    float* cntf     = sm + NG * 16;              // NG

    const int BLK = 256;
    const int gE = (NE + BLK - 1) / BLK;
    const int gN = (NN + BLK - 1) / BLK;
    const int gP32 = (NN + (BLK / 32) - 1) / (BLK / 32);
    const int gP8  = (NN + (BLK / 8) - 1) / (BLK / 8);

    // ---- CSR build + gcn_norm ----
    hipMemsetAsync(deg, 0, (size_t)2 * NN * sizeof(float), stream);  // deg + cnt
    k_deg_cnt<<<gE, BLK, 0, stream>>>(dstp, ew, deg, cnt, NE);
    k_dinv<<<gN, BLK, 0, stream>>>(deg, NN);
    k_scan<<<1, 1024, 0, stream>>>(cnt, row_ptr, cursor, NN);
    k_scatter<<<gE, BLK, 0, stream>>>(srcp, dstp, ew, deg, cursor, csr_src, csr_norm, NE);

    // ---- layer 1: 32 -> 8, K=3 ----
    k_mm<32, 8, false, false><<<gN, BLK, 0, stream>>>(x, W1 + 0 * 256, nullptr, out1, NN);
    k_pull<32><<<gP32, BLK, 0, stream>>>(row_ptr, csr_src, csr_norm, x, bufA, NN);
    k_mm<32, 8, true, false><<<gN, BLK, 0, stream>>>(bufA, W1 + 1 * 256, nullptr, out1, NN);
    k_pull<32><<<gP32, BLK, 0, stream>>>(row_ptr, csr_src, csr_norm, bufA, bufB, NN);
    k_mm<32, 8, true, false><<<gN, BLK, 0, stream>>>(bufB, W1 + 2 * 256, nullptr, out1, NN);
    k_pull<32><<<gP32, BLK, 0, stream>>>(row_ptr, csr_src, csr_norm, bufB, bufA, NN);
    k_mm<32, 8, true, true><<<gN, BLK, 0, stream>>>(bufA, W1 + 3 * 256, b1, out1, NN);

    // ---- layer 2: 8 -> 16, K=3 ----
    k_mm<8, 16, false, false><<<gN, BLK, 0, stream>>>(out1, W2 + 0 * 128, nullptr, out2, NN);
    k_pull<8><<<gP8, BLK, 0, stream>>>(row_ptr, csr_src, csr_norm, out1, bufA, NN);
    k_mm<8, 16, true, false><<<gN, BLK, 0, stream>>>(bufA, W2 + 1 * 128, nullptr, out2, NN);
    k_pull<8><<<gP8, BLK, 0, stream>>>(row_ptr, csr_src, csr_norm, bufA, bufB, NN);
    k_mm<8, 16, true, false><<<gN, BLK, 0, stream>>>(bufB, W2 + 2 * 128, nullptr, out2, NN);
    k_pull<8><<<gP8, BLK, 0, stream>>>(row_ptr, csr_src, csr_norm, bufB, bufA, NN);
    k_mm<8, 16, true, true><<<gN, BLK, 0, stream>>>(bufA, W2 + 3 * 128, b2, out2, NN);

    // ---- pooling + FC ----
    hipMemsetAsync(mx, 0, (size_t)(NG * 16 * 2 + NG) * sizeof(float), stream);
    k_pool<<<gN, BLK, 0, stream>>>(out2, batch, mx, sm, cntf, NN);
    k_final<<<1, 256, 0, stream>>>(mx, sm, cntf, Wfc, bfc, out);
}

// Round 3
// 765.835 us; speedup vs baseline: 13.8748x; 1.8104x over previous
//
#include <hip/hip_runtime.h>

// Problem constants (match reference setup_inputs)
constexpr int NN = 100000;   // nodes
constexpr int NE = 1600000;  // edges
constexpr int NG = 128;      // graphs

// ---------------- CSR build ----------------

// fused: weighted degree (float) + in-edge count (int)
__global__ void k_deg_cnt(const int* __restrict__ dst, const float* __restrict__ w,
                          float* __restrict__ deg, int* __restrict__ cnt, int ne) {
    int e = blockIdx.x * blockDim.x + threadIdx.x;
    if (e < ne) {
        int d = dst[e];
        atomicAdd(&deg[d], w[e]);
        atomicAdd(&cnt[d], 1);
    }
}

__global__ void k_dinv(float* __restrict__ deg, int nn) {
    int i = blockIdx.x * blockDim.x + threadIdx.x;
    if (i < nn) {
        float d = deg[i];
        deg[i] = d > 0.f ? rsqrtf(fmaxf(d, 1e-30f)) : 0.f;
    }
}

// single-block exclusive scan of cnt -> row_ptr (and cursor copy)
__global__ void k_scan(const int* __restrict__ cnt, int* __restrict__ row_ptr,
                       int* __restrict__ cursor, int nn) {
    constexpr int T = 1024;
    __shared__ int ps[T];
    int t = threadIdx.x;
    int chunk = (nn + T - 1) / T;
    int beg = t * chunk;
    int end = min(beg + chunk, nn);
    int s = 0;
    for (int i = beg; i < end; ++i) s += cnt[i];
    ps[t] = s;
    __syncthreads();
    for (int off = 1; off < T; off <<= 1) {
        int v = (t >= off) ? ps[t - off] : 0;
        __syncthreads();
        ps[t] += v;
        __syncthreads();
    }
    int run = (t > 0) ? ps[t - 1] : 0;
    for (int i = beg; i < end; ++i) {
        row_ptr[i] = run;
        cursor[i] = run;
        run += cnt[i];
    }
    if (t == T - 1) row_ptr[nn] = ps[T - 1];
}

// scatter edges into CSR slots; norm computed inline
__global__ void k_scatter(const int* __restrict__ src, const int* __restrict__ dst,
                          const float* __restrict__ w, const float* __restrict__ dinv,
                          int* __restrict__ cursor, int* __restrict__ csr_src,
                          float* __restrict__ csr_norm, int ne) {
    int e = blockIdx.x * blockDim.x + threadIdx.x;
    if (e >= ne) return;
    int s = src[e], d = dst[e];
    int slot = atomicAdd(&cursor[d], 1);
    csr_src[slot] = s;
    csr_norm[slot] = dinv[s] * w[e] * dinv[d];
}

// ---------------- pull propagate ----------------
// one group of F lanes per node; lane j accumulates feature j
template <int F>
__global__ void k_pull(const int* __restrict__ row_ptr, const int* __restrict__ csr_src,
                       const float* __restrict__ csr_norm,
                       const float* __restrict__ hin, float* __restrict__ hout, int nn) {
    int g = blockIdx.x * (blockDim.x / F) + threadIdx.x / F;
    int lane = threadIdx.x & (F - 1);
    if (g >= nn) return;
    int beg = row_ptr[g], end = row_ptr[g + 1];
    float acc0 = 0.f, acc1 = 0.f;
    int e = beg;
    for (; e + 1 < end; e += 2) {
        int s0 = csr_src[e], s1 = csr_src[e + 1];
        float n0 = csr_norm[e], n1 = csr_norm[e + 1];
        acc0 = fmaf(hin[(size_t)s0 * F + lane], n0, acc0);
        acc1 = fmaf(hin[(size_t)s1 * F + lane], n1, acc1);
    }
    if (e < end) {
        int s0 = csr_src[e];
        acc0 = fmaf(hin[(size_t)s0 * F + lane], csr_norm[e], acc0);
    }
    hout[(size_t)g * F + lane] = acc0 + acc1;
}

// ---------------- dense mm (+ optional fused bias/relu) ----------------
template <int FIN, int FOUT, bool ACC, bool EPI>
__global__ void k_mm(const float* __restrict__ h, const float* __restrict__ W,
                     const float* __restrict__ b, float* __restrict__ out, int nn) {
    __shared__ float sW[FIN * FOUT];
    for (int i = threadIdx.x; i < FIN * FOUT; i += blockDim.x) sW[i] = W[i];
    __syncthreads();
    int n = blockIdx.x * blockDim.x + threadIdx.x;
    if (n >= nn) return;
    float hr[FIN];
    const float4* hp = reinterpret_cast<const float4*>(h + (size_t)n * FIN);
#pragma unroll
    for (int f = 0; f < FIN / 4; ++f) {
        float4 v = hp[f];
        hr[4 * f + 0] = v.x; hr[4 * f + 1] = v.y;
        hr[4 * f + 2] = v.z; hr[4 * f + 3] = v.w;
    }
#pragma unroll
    for (int j = 0; j < FOUT; ++j) {
        float acc = 0.f;
#pragma unroll
        for (int i = 0; i < FIN; ++i) acc += hr[i] * sW[i * FOUT + j];
        size_t o = (size_t)n * FOUT + j;
        float r = ACC ? out[o] + acc : acc;
        if (EPI) r = fmaxf(r + b[j], 0.f);
        out[o] = r;
    }
}

// ---------------- pooling + FC (batch is sorted -> contiguous segments) ----------------

// start[g] = first node index of graph g; start[NG] = NN
__global__ void k_bounds(const int* __restrict__ batch, int* __restrict__ start, int nn) {
    int i = blockIdx.x * blockDim.x + threadIdx.x;
    if (i >= nn) return;
    int b = batch[i];
    int prev = (i == 0) ? -1 : batch[i - 1];
    for (int g = prev + 1; g <= b; ++g) start[g] = i;
    if (i == nn - 1) {
        for (int g = b + 1; g <= NG; ++g) start[g] = nn;
    }
}

// one block per graph: segmented max+sum reduction (no atomics) + fused FC
__global__ void k_pool2(const float* __restrict__ h, const int* __restrict__ start,
                        const float* __restrict__ Wfc, const float* __restrict__ bfc,
                        float* __restrict__ out) {
    int g = blockIdx.x;
    int beg = start[g], end = start[g + 1];
    int tid = threadIdx.x;
    int feat = tid & 15, grp = tid >> 4;  // 16 node-groups x 16 features
    // post-ReLU values are >= 0; empty segment -> 0 (matches prior passing behavior)
    float mx = 0.f, sm = 0.f;
    for (int n = beg + grp; n < end; n += 16) {
        float v = h[(size_t)n * 16 + feat];
        mx = fmaxf(mx, v);
        sm += v;
    }
    // reduce the 4 groups inside each wave (lanes differ in bits 4,5)
    mx = fmaxf(mx, __shfl_xor(mx, 16, 64));
    sm += __shfl_xor(sm, 16, 64);
    mx = fmaxf(mx, __shfl_xor(mx, 32, 64));
    sm += __shfl_xor(sm, 32, 64);
    __shared__ float smx[4][16], ssm[4][16];
    int wave = tid >> 6;
    int lane = tid & 63;
    if (lane < 16) { smx[wave][feat] = mx; ssm[wave][feat] = sm; }
    __syncthreads();
    if (tid < 16) {
        float m = fmaxf(fmaxf(smx[0][tid], smx[1][tid]), fmaxf(smx[2][tid], smx[3][tid]));
        float s = ssm[0][tid] + ssm[1][tid] + ssm[2][tid] + ssm[3][tid];
        smx[0][tid] = m;
        ssm[0][tid] = (end > beg) ? s / (float)(end - beg) : 0.f;
    }
    __syncthreads();
    if (tid < 2) {
        float acc = bfc[tid];
#pragma unroll
        for (int i = 0; i < 16; ++i) acc += smx[0][i] * Wfc[i * 2 + tid];
#pragma unroll
        for (int i = 0; i < 16; ++i) acc += ssm[0][i] * Wfc[(16 + i) * 2 + tid];
        out[g * 2 + tid] = acc;
    }
}

// ---------------- launch ----------------

extern "C" void kernel_launch(void* const* d_in, const int* in_sizes, int n_in,
                              void* d_out, int out_size, void* d_ws, size_t ws_size,
                              hipStream_t stream) {
    const float* x    = (const float*)d_in[0];           // NN x 32
    const int*   eidx = (const int*)d_in[1];             // 2 x NE
    const int*   srcp = eidx;
    const int*   dstp = eidx + NE;
    const int*   batch= (const int*)d_in[2];             // NN
    const float* ew   = (const float*)d_in[3];           // NE
    const float* W1   = (const float*)d_in[4];           // 4 x 32 x 8
    const float* b1   = (const float*)d_in[5];           // 8
    const float* W2   = (const float*)d_in[6];           // 4 x 8 x 16
    const float* b2   = (const float*)d_in[7];           // 16
    const float* Wfc  = (const float*)d_in[8];           // 32 x 2
    const float* bfc  = (const float*)d_in[9];           // 2
    float* out = (float*)d_out;                          // NG x 2

    // workspace layout (4-byte units)
    float* deg      = (float*)d_ws;              // NN
    int*   cnt      = (int*)(deg + NN);          // NN
    int*   row_ptr  = cnt + NN;                  // NN + 4 (pad)
    int*   cursor   = row_ptr + NN + 4;          // NN
    int*   csr_src  = cursor + NN;               // NE
    float* csr_norm = (float*)(csr_src + NE);    // NE
    float* bufA     = csr_norm + NE;             // NN*32
    float* bufB     = bufA + (size_t)NN * 32;    // NN*32
    float* out1     = bufB + (size_t)NN * 32;    // NN*8
    float* out2     = out1 + (size_t)NN * 8;     // NN*16
    int*   gstart   = (int*)(out2 + (size_t)NN * 16);  // NG+1

    const int BLK = 256;
    const int gE = (NE + BLK - 1) / BLK;
    const int gN = (NN + BLK - 1) / BLK;
    const int gP32 = (NN + (BLK / 32) - 1) / (BLK / 32);
    const int gP8  = (NN + (BLK / 8) - 1) / (BLK / 8);

    // ---- CSR build + gcn_norm ----
    hipMemsetAsync(deg, 0, (size_t)2 * NN * sizeof(float), stream);  // deg + cnt
    k_deg_cnt<<<gE, BLK, 0, stream>>>(dstp, ew, deg, cnt, NE);
    k_dinv<<<gN, BLK, 0, stream>>>(deg, NN);
    k_scan<<<1, 1024, 0, stream>>>(cnt, row_ptr, cursor, NN);
    k_scatter<<<gE, BLK, 0, stream>>>(srcp, dstp, ew, deg, cursor, csr_src, csr_norm, NE);
    k_bounds<<<gN, BLK, 0, stream>>>(batch, gstart, NN);

    // ---- layer 1: 32 -> 8, K=3 ----
    k_mm<32, 8, false, false><<<gN, BLK, 0, stream>>>(x, W1 + 0 * 256, nullptr, out1, NN);
    k_pull<32><<<gP32, BLK, 0, stream>>>(row_ptr, csr_src, csr_norm, x, bufA, NN);
    k_mm<32, 8, true, false><<<gN, BLK, 0, stream>>>(bufA, W1 + 1 * 256, nullptr, out1, NN);
    k_pull<32><<<gP32, BLK, 0, stream>>>(row_ptr, csr_src, csr_norm, bufA, bufB, NN);
    k_mm<32, 8, true, false><<<gN, BLK, 0, stream>>>(bufB, W1 + 2 * 256, nullptr, out1, NN);
    k_pull<32><<<gP32, BLK, 0, stream>>>(row_ptr, csr_src, csr_norm, bufB, bufA, NN);
    k_mm<32, 8, true, true><<<gN, BLK, 0, stream>>>(bufA, W1 + 3 * 256, b1, out1, NN);

    // ---- layer 2: 8 -> 16, K=3 ----
    k_mm<8, 16, false, false><<<gN, BLK, 0, stream>>>(out1, W2 + 0 * 128, nullptr, out2, NN);
    k_pull<8><<<gP8, BLK, 0, stream>>>(row_ptr, csr_src, csr_norm, out1, bufA, NN);
    k_mm<8, 16, true, false><<<gN, BLK, 0, stream>>>(bufA, W2 + 1 * 128, nullptr, out2, NN);
    k_pull<8><<<gP8, BLK, 0, stream>>>(row_ptr, csr_src, csr_norm, bufA, bufB, NN);
    k_mm<8, 16, true, false><<<gN, BLK, 0, stream>>>(bufB, W2 + 2 * 128, nullptr, out2, NN);
    k_pull<8><<<gP8, BLK, 0, stream>>>(row_ptr, csr_src, csr_norm, bufB, bufA, NN);
    k_mm<8, 16, true, true><<<gN, BLK, 0, stream>>>(bufA, W2 + 3 * 128, b2, out2, NN);

    // ---- pooling + fused FC (no atomics) ----
    k_pool2<<<NG, 256, 0, stream>>>(out2, gstart, Wfc, bfc, out);
}

// Round 4
// 587.432 us; speedup vs baseline: 18.0886x; 1.3037x over previous
//
#include <hip/hip_runtime.h>

// Problem constants (match reference setup_inputs)
constexpr int NN = 100000;   // nodes
constexpr int NE = 1600000;  // edges
constexpr int NG = 128;      // graphs

constexpr int SCAN_T = 256;
constexpr int SCAN_B = (NN + SCAN_T - 1) / SCAN_T;  // 391

// ---------------- CSR build ----------------

// fused: weighted degree (float) + in-edge count (int)
__global__ void k_deg_cnt(const int* __restrict__ dst, const float* __restrict__ w,
                          float* __restrict__ deg, int* __restrict__ cnt, int ne) {
    int e = blockIdx.x * blockDim.x + threadIdx.x;
    if (e < ne) {
        int d = dst[e];
        atomicAdd(&deg[d], w[e]);
        atomicAdd(&cnt[d], 1);
    }
}

__global__ void k_dinv(float* __restrict__ deg, int nn) {
    int i = blockIdx.x * blockDim.x + threadIdx.x;
    if (i < nn) {
        float d = deg[i];
        deg[i] = d > 0.f ? rsqrtf(fmaxf(d, 1e-30f)) : 0.f;
    }
}

// ---- multi-block exclusive scan of cnt -> row_ptr (+cursor) ----

// phase 1: per-block tree reduction
__global__ void k_scan1(const int* __restrict__ cnt, int* __restrict__ bsum, int nn) {
    __shared__ int s[SCAN_T];
    int i = blockIdx.x * SCAN_T + threadIdx.x;
    s[threadIdx.x] = (i < nn) ? cnt[i] : 0;
    __syncthreads();
    for (int off = SCAN_T / 2; off > 0; off >>= 1) {
        if (threadIdx.x < off) s[threadIdx.x] += s[threadIdx.x + off];
        __syncthreads();
    }
    if (threadIdx.x == 0) bsum[blockIdx.x] = s[0];
}

// phase 2: single-block exclusive scan of the block sums (nb <= 512)
__global__ void k_scan2(int* __restrict__ bsum, int nb) {
    __shared__ int s[512];
    int t = threadIdx.x;
    s[t] = (t < nb) ? bsum[t] : 0;
    __syncthreads();
    for (int off = 1; off < 512; off <<= 1) {
        int v = (t >= off) ? s[t - off] : 0;
        __syncthreads();
        s[t] += v;
        __syncthreads();
    }
    if (t < nb) bsum[t] = (t > 0) ? s[t - 1] : 0;
}

// phase 3: block-local exclusive scan + block base -> row_ptr, cursor
__global__ void k_scan3(const int* __restrict__ cnt, const int* __restrict__ bsum,
                        int* __restrict__ row_ptr, int* __restrict__ cursor, int nn) {
    __shared__ int s[SCAN_T];
    int t = threadIdx.x;
    int i = blockIdx.x * SCAN_T + t;
    int v = (i < nn) ? cnt[i] : 0;
    s[t] = v;
    __syncthreads();
    for (int off = 1; off < SCAN_T; off <<= 1) {
        int u = (t >= off) ? s[t - off] : 0;
        __syncthreads();
        s[t] += u;
        __syncthreads();
    }
    int incl = s[t];
    int base = bsum[blockIdx.x];
    if (i < nn) {
        int e = base + incl - v;
        row_ptr[i] = e;
        cursor[i] = e;
        if (i == nn - 1) row_ptr[nn] = base + incl;
    }
}

// scatter edges into CSR slots; norm computed inline
__global__ void k_scatter(const int* __restrict__ src, const int* __restrict__ dst,
                          const float* __restrict__ w, const float* __restrict__ dinv,
                          int* __restrict__ cursor, int* __restrict__ csr_src,
                          float* __restrict__ csr_norm, int ne) {
    int e = blockIdx.x * blockDim.x + threadIdx.x;
    if (e >= ne) return;
    int s = src[e], d = dst[e];
    int slot = atomicAdd(&cursor[d], 1);
    csr_src[slot] = s;
    csr_norm[slot] = dinv[s] * w[e] * dinv[d];
}

// ---------------- pull propagate ----------------
// one group of F lanes per node; lane j accumulates feature j
template <int F>
__global__ void k_pull(const int* __restrict__ row_ptr, const int* __restrict__ csr_src,
                       const float* __restrict__ csr_norm,
                       const float* __restrict__ hin, float* __restrict__ hout, int nn) {
    int g = blockIdx.x * (blockDim.x / F) + threadIdx.x / F;
    int lane = threadIdx.x & (F - 1);
    if (g >= nn) return;
    int beg = row_ptr[g], end = row_ptr[g + 1];
    float acc0 = 0.f, acc1 = 0.f;
    int e = beg;
    for (; e + 1 < end; e += 2) {
        int s0 = csr_src[e], s1 = csr_src[e + 1];
        float n0 = csr_norm[e], n1 = csr_norm[e + 1];
        acc0 = fmaf(hin[(size_t)s0 * F + lane], n0, acc0);
        acc1 = fmaf(hin[(size_t)s1 * F + lane], n1, acc1);
    }
    if (e < end) {
        int s0 = csr_src[e];
        acc0 = fmaf(hin[(size_t)s0 * F + lane], csr_norm[e], acc0);
    }
    hout[(size_t)g * F + lane] = acc0 + acc1;
}

// ---------------- dense mm (+ optional fused bias/relu) ----------------
template <int FIN, int FOUT, bool ACC, bool EPI>
__global__ void k_mm(const float* __restrict__ h, const float* __restrict__ W,
                     const float* __restrict__ b, float* __restrict__ out, int nn) {
    __shared__ float sW[FIN * FOUT];
    for (int i = threadIdx.x; i < FIN * FOUT; i += blockDim.x) sW[i] = W[i];
    __syncthreads();
    int n = blockIdx.x * blockDim.x + threadIdx.x;
    if (n >= nn) return;
    float hr[FIN];
    const float4* hp = reinterpret_cast<const float4*>(h + (size_t)n * FIN);
#pragma unroll
    for (int f = 0; f < FIN / 4; ++f) {
        float4 v = hp[f];
        hr[4 * f + 0] = v.x; hr[4 * f + 1] = v.y;
        hr[4 * f + 2] = v.z; hr[4 * f + 3] = v.w;
    }
#pragma unroll
    for (int j = 0; j < FOUT; ++j) {
        float acc = 0.f;
#pragma unroll
        for (int i = 0; i < FIN; ++i) acc += hr[i] * sW[i * FOUT + j];
        size_t o = (size_t)n * FOUT + j;
        float r = ACC ? out[o] + acc : acc;
        if (EPI) r = fmaxf(r + b[j], 0.f);
        out[o] = r;
    }
}

// ---------------- pooling + FC (batch is sorted -> contiguous segments) ----------------

// start[g] = first node index of graph g; start[NG] = NN
__global__ void k_bounds(const int* __restrict__ batch, int* __restrict__ start, int nn) {
    int i = blockIdx.x * blockDim.x + threadIdx.x;
    if (i >= nn) return;
    int b = batch[i];
    int prev = (i == 0) ? -1 : batch[i - 1];
    for (int g = prev + 1; g <= b; ++g) start[g] = i;
    if (i == nn - 1) {
        for (int g = b + 1; g <= NG; ++g) start[g] = nn;
    }
}

// one block per graph: segmented max+sum reduction (no atomics) + fused FC
__global__ void k_pool2(const float* __restrict__ h, const int* __restrict__ start,
                        const float* __restrict__ Wfc, const float* __restrict__ bfc,
                        float* __restrict__ out) {
    int g = blockIdx.x;
    int beg = start[g], end = start[g + 1];
    int tid = threadIdx.x;
    int feat = tid & 15, grp = tid >> 4;  // 16 node-groups x 16 features
    // post-ReLU values are >= 0; empty segment -> 0
    float mx = 0.f, sm = 0.f;
    for (int n = beg + grp; n < end; n += 16) {
        float v = h[(size_t)n * 16 + feat];
        mx = fmaxf(mx, v);
        sm += v;
    }
    // reduce the 4 groups inside each wave (lanes differ in bits 4,5)
    mx = fmaxf(mx, __shfl_xor(mx, 16, 64));
    sm += __shfl_xor(sm, 16, 64);
    mx = fmaxf(mx, __shfl_xor(mx, 32, 64));
    sm += __shfl_xor(sm, 32, 64);
    __shared__ float smx[4][16], ssm[4][16];
    int wave = tid >> 6;
    int lane = tid & 63;
    if (lane < 16) { smx[wave][feat] = mx; ssm[wave][feat] = sm; }
    __syncthreads();
    if (tid < 16) {
        float m = fmaxf(fmaxf(smx[0][tid], smx[1][tid]), fmaxf(smx[2][tid], smx[3][tid]));
        float s = ssm[0][tid] + ssm[1][tid] + ssm[2][tid] + ssm[3][tid];
        smx[0][tid] = m;
        ssm[0][tid] = (end > beg) ? s / (float)(end - beg) : 0.f;
    }
    __syncthreads();
    if (tid < 2) {
        float acc = bfc[tid];
#pragma unroll
        for (int i = 0; i < 16; ++i) acc += smx[0][i] * Wfc[i * 2 + tid];
#pragma unroll
        for (int i = 0; i < 16; ++i) acc += ssm[0][i] * Wfc[(16 + i) * 2 + tid];
        out[g * 2 + tid] = acc;
    }
}

// ---------------- launch ----------------

extern "C" void kernel_launch(void* const* d_in, const int* in_sizes, int n_in,
                              void* d_out, int out_size, void* d_ws, size_t ws_size,
                              hipStream_t stream) {
    const float* x    = (const float*)d_in[0];           // NN x 32
    const int*   eidx = (const int*)d_in[1];             // 2 x NE
    const int*   srcp = eidx;
    const int*   dstp = eidx + NE;
    const int*   batch= (const int*)d_in[2];             // NN
    const float* ew   = (const float*)d_in[3];           // NE
    const float* W1   = (const float*)d_in[4];           // 4 x 32 x 8
    const float* b1   = (const float*)d_in[5];           // 8
    const float* W2   = (const float*)d_in[6];           // 4 x 8 x 16
    const float* b2   = (const float*)d_in[7];           // 16
    const float* Wfc  = (const float*)d_in[8];           // 32 x 2
    const float* bfc  = (const float*)d_in[9];           // 2
    float* out = (float*)d_out;                          // NG x 2

    // workspace layout (4-byte units)
    float* deg      = (float*)d_ws;              // NN
    int*   cnt      = (int*)(deg + NN);          // NN
    int*   row_ptr  = cnt + NN;                  // NN + 4 (pad)
    int*   cursor   = row_ptr + NN + 4;          // NN
    int*   csr_src  = cursor + NN;               // NE
    float* csr_norm = (float*)(csr_src + NE);    // NE
    float* bufA     = csr_norm + NE;             // NN*32
    float* bufB     = bufA + (size_t)NN * 32;    // NN*32
    float* out1     = bufB + (size_t)NN * 32;    // NN*8
    float* out2     = out1 + (size_t)NN * 8;     // NN*16
    int*   gstart   = (int*)(out2 + (size_t)NN * 16);  // NG+1
    int*   bsum     = gstart + NG + 4;           // SCAN_B

    const int BLK = 256;
    const int gE = (NE + BLK - 1) / BLK;
    const int gN = (NN + BLK - 1) / BLK;
    const int gP32 = (NN + (BLK / 32) - 1) / (BLK / 32);
    const int gP8  = (NN + (BLK / 8) - 1) / (BLK / 8);

    // ---- CSR build + gcn_norm ----
    hipMemsetAsync(deg, 0, (size_t)2 * NN * sizeof(float), stream);  // deg + cnt
    k_deg_cnt<<<gE, BLK, 0, stream>>>(dstp, ew, deg, cnt, NE);
    k_dinv<<<gN, BLK, 0, stream>>>(deg, NN);
    k_scan1<<<SCAN_B, SCAN_T, 0, stream>>>(cnt, bsum, NN);
    k_scan2<<<1, 512, 0, stream>>>(bsum, SCAN_B);
    k_scan3<<<SCAN_B, SCAN_T, 0, stream>>>(cnt, bsum, row_ptr, cursor, NN);
    k_scatter<<<gE, BLK, 0, stream>>>(srcp, dstp, ew, deg, cursor, csr_src, csr_norm, NE);
    k_bounds<<<gN, BLK, 0, stream>>>(batch, gstart, NN);

    // ---- layer 1: 32 -> 8, K=3 ----
    k_mm<32, 8, false, false><<<gN, BLK, 0, stream>>>(x, W1 + 0 * 256, nullptr, out1, NN);
    k_pull<32><<<gP32, BLK, 0, stream>>>(row_ptr, csr_src, csr_norm, x, bufA, NN);
    k_mm<32, 8, true, false><<<gN, BLK, 0, stream>>>(bufA, W1 + 1 * 256, nullptr, out1, NN);
    k_pull<32><<<gP32, BLK, 0, stream>>>(row_ptr, csr_src, csr_norm, bufA, bufB, NN);
    k_mm<32, 8, true, false><<<gN, BLK, 0, stream>>>(bufB, W1 + 2 * 256, nullptr, out1, NN);
    k_pull<32><<<gP32, BLK, 0, stream>>>(row_ptr, csr_src, csr_norm, bufB, bufA, NN);
    k_mm<32, 8, true, true><<<gN, BLK, 0, stream>>>(bufA, W1 + 3 * 256, b1, out1, NN);

    // ---- layer 2: 8 -> 16, K=3 ----
    k_mm<8, 16, false, false><<<gN, BLK, 0, stream>>>(out1, W2 + 0 * 128, nullptr, out2, NN);
    k_pull<8><<<gP8, BLK, 0, stream>>>(row_ptr, csr_src, csr_norm, out1, bufA, NN);
    k_mm<8, 16, true, false><<<gN, BLK, 0, stream>>>(bufA, W2 + 1 * 128, nullptr, out2, NN);
    k_pull<8><<<gP8, BLK, 0, stream>>>(row_ptr, csr_src, csr_norm, bufA, bufB, NN);
    k_mm<8, 16, true, false><<<gN, BLK, 0, stream>>>(bufB, W2 + 2 * 128, nullptr, out2, NN);
    k_pull<8><<<gP8, BLK, 0, stream>>>(row_ptr, csr_src, csr_norm, bufB, bufA, NN);
    k_mm<8, 16, true, true><<<gN, BLK, 0, stream>>>(bufA, W2 + 3 * 128, b2, out2, NN);

    // ---- pooling + fused FC (no atomics) ----
    k_pool2<<<NG, 256, 0, stream>>>(out2, gstart, Wfc, bfc, out);
}

// Round 5
// 436.281 us; speedup vs baseline: 24.3554x; 1.3465x over previous
//
#include <hip/hip_runtime.h>

// Problem constants (match reference setup_inputs)
constexpr int NN = 100000;   // nodes
constexpr int NE = 1600000;  // edges
constexpr int NG = 128;      // graphs

constexpr int SCAN_T = 256;
constexpr int SCAN_B = (NN + SCAN_T - 1) / SCAN_T;  // 391

// interleaved CSR entry: src index + (weight, later norm)
struct __align__(8) Ent { int s; float nw; };

// ---------------- CSR build ----------------

// the only atomic pass: in-degree count + per-edge rank
__global__ void k_rank(const int* __restrict__ dst, int* __restrict__ cnt,
                       int* __restrict__ rank, int ne) {
    int e = blockIdx.x * blockDim.x + threadIdx.x;
    if (e < ne) rank[e] = atomicAdd(&cnt[dst[e]], 1);
}

// ---- multi-block exclusive scan of cnt -> row_ptr ----

__global__ void k_scan1(const int* __restrict__ cnt, int* __restrict__ bsum, int nn) {
    __shared__ int s[SCAN_T];
    int i = blockIdx.x * SCAN_T + threadIdx.x;
    s[threadIdx.x] = (i < nn) ? cnt[i] : 0;
    __syncthreads();
    for (int off = SCAN_T / 2; off > 0; off >>= 1) {
        if (threadIdx.x < off) s[threadIdx.x] += s[threadIdx.x + off];
        __syncthreads();
    }
    if (threadIdx.x == 0) bsum[blockIdx.x] = s[0];
}

__global__ void k_scan2(int* __restrict__ bsum, int nb) {
    __shared__ int s[512];
    int t = threadIdx.x;
    s[t] = (t < nb) ? bsum[t] : 0;
    __syncthreads();
    for (int off = 1; off < 512; off <<= 1) {
        int v = (t >= off) ? s[t - off] : 0;
        __syncthreads();
        s[t] += v;
        __syncthreads();
    }
    if (t < nb) bsum[t] = (t > 0) ? s[t - 1] : 0;
}

__global__ void k_scan3(const int* __restrict__ cnt, const int* __restrict__ bsum,
                        int* __restrict__ row_ptr, int nn) {
    __shared__ int s[SCAN_T];
    int t = threadIdx.x;
    int i = blockIdx.x * SCAN_T + t;
    int v = (i < nn) ? cnt[i] : 0;
    s[t] = v;
    __syncthreads();
    for (int off = 1; off < SCAN_T; off <<= 1) {
        int u = (t >= off) ? s[t - off] : 0;
        __syncthreads();
        s[t] += u;
        __syncthreads();
    }
    int incl = s[t];
    int base = bsum[blockIdx.x];
    if (i < nn) {
        row_ptr[i] = base + incl - v;
        if (i == nn - 1) row_ptr[nn] = base + incl;
    }
}

// atomic-free scatter into CSR slots (interleaved {src, w})
__global__ void k_scatter2(const int* __restrict__ src, const int* __restrict__ dst,
                           const float* __restrict__ w, const int* __restrict__ row_ptr,
                           const int* __restrict__ rank, Ent* __restrict__ csr, int ne) {
    int e = blockIdx.x * blockDim.x + threadIdx.x;
    if (e >= ne) return;
    int slot = row_ptr[dst[e]] + rank[e];
    Ent en; en.s = src[e]; en.nw = w[e];
    csr[slot] = en;
}

// weighted in-degree from CSR segments -> dinv (no atomics); 8 lanes per node
__global__ void k_degi(const int* __restrict__ row_ptr, const Ent* __restrict__ csr,
                       float* __restrict__ dinv, int nn) {
    int tid = blockIdx.x * blockDim.x + threadIdx.x;
    int n = tid >> 3, lane = tid & 7;
    if (n >= nn) return;
    int beg = row_ptr[n], end = row_ptr[n + 1];
    float s = 0.f;
    for (int e = beg + lane; e < end; e += 8) s += csr[e].nw;
    s += __shfl_xor(s, 1, 64);
    s += __shfl_xor(s, 2, 64);
    s += __shfl_xor(s, 4, 64);
    if (lane == 0) dinv[n] = s > 0.f ? rsqrtf(fmaxf(s, 1e-30f)) : 0.f;
}

// rewrite entry weight -> norm = dinv[src]*w*dinv[dst] in place; 8 lanes per node
__global__ void k_norm2(const int* __restrict__ row_ptr, Ent* __restrict__ csr,
                        const float* __restrict__ dinv, int nn) {
    int tid = blockIdx.x * blockDim.x + threadIdx.x;
    int n = tid >> 3, lane = tid & 7;
    if (n >= nn) return;
    int beg = row_ptr[n], end = row_ptr[n + 1];
    float dn = dinv[n];
    for (int e = beg + lane; e < end; e += 8) {
        Ent en = csr[e];
        csr[e].nw = dinv[en.s] * en.nw * dn;
    }
}

// ---------------- pull propagate ----------------
// one group of F lanes per node; lane j accumulates feature j
template <int F>
__global__ void k_pull(const int* __restrict__ row_ptr, const Ent* __restrict__ csr,
                       const float* __restrict__ hin, float* __restrict__ hout, int nn) {
    int g = blockIdx.x * (blockDim.x / F) + threadIdx.x / F;
    int lane = threadIdx.x & (F - 1);
    if (g >= nn) return;
    int beg = row_ptr[g], end = row_ptr[g + 1];
    float acc0 = 0.f, acc1 = 0.f;
    int e = beg;
    for (; e + 1 < end; e += 2) {
        Ent e0 = csr[e], e1 = csr[e + 1];
        acc0 = fmaf(hin[(size_t)e0.s * F + lane], e0.nw, acc0);
        acc1 = fmaf(hin[(size_t)e1.s * F + lane], e1.nw, acc1);
    }
    if (e < end) {
        Ent e0 = csr[e];
        acc0 = fmaf(hin[(size_t)e0.s * F + lane], e0.nw, acc0);
    }
    hout[(size_t)g * F + lane] = acc0 + acc1;
}

// ---------------- dense mm (+ optional fused bias/relu) ----------------
template <int FIN, int FOUT, bool ACC, bool EPI>
__global__ void k_mm(const float* __restrict__ h, const float* __restrict__ W,
                     const float* __restrict__ b, float* __restrict__ out, int nn) {
    __shared__ float sW[FIN * FOUT];
    for (int i = threadIdx.x; i < FIN * FOUT; i += blockDim.x) sW[i] = W[i];
    __syncthreads();
    int n = blockIdx.x * blockDim.x + threadIdx.x;
    if (n >= nn) return;
    float hr[FIN];
    const float4* hp = reinterpret_cast<const float4*>(h + (size_t)n * FIN);
#pragma unroll
    for (int f = 0; f < FIN / 4; ++f) {
        float4 v = hp[f];
        hr[4 * f + 0] = v.x; hr[4 * f + 1] = v.y;
        hr[4 * f + 2] = v.z; hr[4 * f + 3] = v.w;
    }
#pragma unroll
    for (int j = 0; j < FOUT; ++j) {
        float acc = 0.f;
#pragma unroll
        for (int i = 0; i < FIN; ++i) acc += hr[i] * sW[i * FOUT + j];
        size_t o = (size_t)n * FOUT + j;
        float r = ACC ? out[o] + acc : acc;
        if (EPI) r = fmaxf(r + b[j], 0.f);
        out[o] = r;
    }
}

// ---------------- pooling + FC (batch is sorted -> contiguous segments) ----------------

__global__ void k_bounds(const int* __restrict__ batch, int* __restrict__ start, int nn) {
    int i = blockIdx.x * blockDim.x + threadIdx.x;
    if (i >= nn) return;
    int b = batch[i];
    int prev = (i == 0) ? -1 : batch[i - 1];
    for (int g = prev + 1; g <= b; ++g) start[g] = i;
    if (i == nn - 1) {
        for (int g = b + 1; g <= NG; ++g) start[g] = nn;
    }
}

// one block per graph: segmented max+sum reduction (no atomics) + fused FC
__global__ void k_pool2(const float* __restrict__ h, const int* __restrict__ start,
                        const float* __restrict__ Wfc, const float* __restrict__ bfc,
                        float* __restrict__ out) {
    int g = blockIdx.x;
    int beg = start[g], end = start[g + 1];
    int tid = threadIdx.x;
    int feat = tid & 15, grp = tid >> 4;  // 16 node-groups x 16 features
    float mx = 0.f, sm = 0.f;  // post-ReLU values are >= 0
    for (int n = beg + grp; n < end; n += 16) {
        float v = h[(size_t)n * 16 + feat];
        mx = fmaxf(mx, v);
        sm += v;
    }
    mx = fmaxf(mx, __shfl_xor(mx, 16, 64));
    sm += __shfl_xor(sm, 16, 64);
    mx = fmaxf(mx, __shfl_xor(mx, 32, 64));
    sm += __shfl_xor(sm, 32, 64);
    __shared__ float smx[4][16], ssm[4][16];
    int wave = tid >> 6;
    int lane = tid & 63;
    if (lane < 16) { smx[wave][feat] = mx; ssm[wave][feat] = sm; }
    __syncthreads();
    if (tid < 16) {
        float m = fmaxf(fmaxf(smx[0][tid], smx[1][tid]), fmaxf(smx[2][tid], smx[3][tid]));
        float s = ssm[0][tid] + ssm[1][tid] + ssm[2][tid] + ssm[3][tid];
        smx[0][tid] = m;
        ssm[0][tid] = (end > beg) ? s / (float)(end - beg) : 0.f;
    }
    __syncthreads();
    if (tid < 2) {
        float acc = bfc[tid];
#pragma unroll
        for (int i = 0; i < 16; ++i) acc += smx[0][i] * Wfc[i * 2 + tid];
#pragma unroll
        for (int i = 0; i < 16; ++i) acc += ssm[0][i] * Wfc[(16 + i) * 2 + tid];
        out[g * 2 + tid] = acc;
    }
}

// ---------------- launch ----------------

extern "C" void kernel_launch(void* const* d_in, const int* in_sizes, int n_in,
                              void* d_out, int out_size, void* d_ws, size_t ws_size,
                              hipStream_t stream) {
    const float* x    = (const float*)d_in[0];           // NN x 32
    const int*   eidx = (const int*)d_in[1];             // 2 x NE
    const int*   srcp = eidx;
    const int*   dstp = eidx + NE;
    const int*   batch= (const int*)d_in[2];             // NN
    const float* ew   = (const float*)d_in[3];           // NE
    const float* W1   = (const float*)d_in[4];           // 4 x 32 x 8
    const float* b1   = (const float*)d_in[5];           // 8
    const float* W2   = (const float*)d_in[6];           // 4 x 8 x 16
    const float* b2   = (const float*)d_in[7];           // 16
    const float* Wfc  = (const float*)d_in[8];           // 32 x 2
    const float* bfc  = (const float*)d_in[9];           // 2
    float* out = (float*)d_out;                          // NG x 2

    // workspace layout (4-byte units; csr kept 8B-aligned)
    float* dinv     = (float*)d_ws;              // NN
    int*   cnt      = (int*)(dinv + NN);         // NN
    int*   row_ptr  = cnt + NN;                  // NN + 4
    int*   rank     = row_ptr + NN + 4;          // NE
    Ent*   csr      = (Ent*)(rank + NE);         // NE entries (2*NE words)
    float* bufA     = (float*)(csr + NE);        // NN*32
    float* bufB     = bufA + (size_t)NN * 32;    // NN*32
    float* out1     = bufB + (size_t)NN * 32;    // NN*8
    float* out2     = out1 + (size_t)NN * 8;     // NN*16
    int*   gstart   = (int*)(out2 + (size_t)NN * 16);  // NG+1
    int*   bsum     = gstart + NG + 4;           // SCAN_B

    const int BLK = 256;
    const int gE = (NE + BLK - 1) / BLK;
    const int gN = (NN + BLK - 1) / BLK;
    const int gP32 = (NN + (BLK / 32) - 1) / (BLK / 32);
    const int gP8  = (NN + (BLK / 8) - 1) / (BLK / 8);
    const int gN8  = (NN * 8 + BLK - 1) / BLK;   // 8 lanes per node

    // ---- CSR build + gcn_norm (single atomic pass) ----
    hipMemsetAsync(cnt, 0, (size_t)NN * sizeof(int), stream);
    k_rank<<<gE, BLK, 0, stream>>>(dstp, cnt, rank, NE);
    k_scan1<<<SCAN_B, SCAN_T, 0, stream>>>(cnt, bsum, NN);
    k_scan2<<<1, 512, 0, stream>>>(bsum, SCAN_B);
    k_scan3<<<SCAN_B, SCAN_T, 0, stream>>>(cnt, bsum, row_ptr, NN);
    k_scatter2<<<gE, BLK, 0, stream>>>(srcp, dstp, ew, row_ptr, rank, csr, NE);
    k_degi<<<gN8, BLK, 0, stream>>>(row_ptr, csr, dinv, NN);
    k_norm2<<<gN8, BLK, 0, stream>>>(row_ptr, csr, dinv, NN);
    k_bounds<<<gN, BLK, 0, stream>>>(batch, gstart, NN);

    // ---- layer 1: 32 -> 8, K=3 ----
    k_mm<32, 8, false, false><<<gN, BLK, 0, stream>>>(x, W1 + 0 * 256, nullptr, out1, NN);
    k_pull<32><<<gP32, BLK, 0, stream>>>(row_ptr, csr, x, bufA, NN);
    k_mm<32, 8, true, false><<<gN, BLK, 0, stream>>>(bufA, W1 + 1 * 256, nullptr, out1, NN);
    k_pull<32><<<gP32, BLK, 0, stream>>>(row_ptr, csr, bufA, bufB, NN);
    k_mm<32, 8, true, false><<<gN, BLK, 0, stream>>>(bufB, W1 + 2 * 256, nullptr, out1, NN);
    k_pull<32><<<gP32, BLK, 0, stream>>>(row_ptr, csr, bufB, bufA, NN);
    k_mm<32, 8, true, true><<<gN, BLK, 0, stream>>>(bufA, W1 + 3 * 256, b1, out1, NN);

    // ---- layer 2: 8 -> 16, K=3 ----
    k_mm<8, 16, false, false><<<gN, BLK, 0, stream>>>(out1, W2 + 0 * 128, nullptr, out2, NN);
    k_pull<8><<<gP8, BLK, 0, stream>>>(row_ptr, csr, out1, bufA, NN);
    k_mm<8, 16, true, false><<<gN, BLK, 0, stream>>>(bufA, W2 + 1 * 128, nullptr, out2, NN);
    k_pull<8><<<gP8, BLK, 0, stream>>>(row_ptr, csr, bufA, bufB, NN);
    k_mm<8, 16, true, false><<<gN, BLK, 0, stream>>>(bufB, W2 + 2 * 128, nullptr, out2, NN);
    k_pull<8><<<gP8, BLK, 0, stream>>>(row_ptr, csr, bufB, bufA, NN);
    k_mm<8, 16, true, true><<<gN, BLK, 0, stream>>>(bufA, W2 + 3 * 128, b2, out2, NN);

    // ---- pooling + fused FC (no atomics) ----
    k_pool2<<<NG, 256, 0, stream>>>(out2, gstart, Wfc, bfc, out);
}

// Round 6
// 362.201 us; speedup vs baseline: 29.3368x; 1.2045x over previous
//
#include <hip/hip_runtime.h>

// Problem constants (match reference setup_inputs)
constexpr int NN = 100000;   // nodes
constexpr int NE = 1600000;  // edges
constexpr int NG = 128;      // graphs

constexpr int SCAN_T = 256;
constexpr int SCAN_B = (NN + SCAN_T - 1) / SCAN_T;  // 391

// interleaved CSR entry: src index + (weight, later norm)
struct __align__(8) Ent { int s; float nw; };

// ---------------- CSR build ----------------

// the only atomic pass: in-degree count + per-edge rank
__global__ void k_rank(const int* __restrict__ dst, int* __restrict__ cnt,
                       int* __restrict__ rank, int ne) {
    int e = blockIdx.x * blockDim.x + threadIdx.x;
    if (e < ne) rank[e] = atomicAdd(&cnt[dst[e]], 1);
}

// ---- multi-block exclusive scan of cnt -> row_ptr ----

__global__ void k_scan1(const int* __restrict__ cnt, int* __restrict__ bsum, int nn) {
    __shared__ int s[SCAN_T];
    int i = blockIdx.x * SCAN_T + threadIdx.x;
    s[threadIdx.x] = (i < nn) ? cnt[i] : 0;
    __syncthreads();
    for (int off = SCAN_T / 2; off > 0; off >>= 1) {
        if (threadIdx.x < off) s[threadIdx.x] += s[threadIdx.x + off];
        __syncthreads();
    }
    if (threadIdx.x == 0) bsum[blockIdx.x] = s[0];
}

__global__ void k_scan2(int* __restrict__ bsum, int nb) {
    __shared__ int s[512];
    int t = threadIdx.x;
    s[t] = (t < nb) ? bsum[t] : 0;
    __syncthreads();
    for (int off = 1; off < 512; off <<= 1) {
        int v = (t >= off) ? s[t - off] : 0;
        __syncthreads();
        s[t] += v;
        __syncthreads();
    }
    if (t < nb) bsum[t] = (t > 0) ? s[t - 1] : 0;
}

__global__ void k_scan3(const int* __restrict__ cnt, const int* __restrict__ bsum,
                        int* __restrict__ row_ptr, int nn) {
    __shared__ int s[SCAN_T];
    int t = threadIdx.x;
    int i = blockIdx.x * SCAN_T + t;
    int v = (i < nn) ? cnt[i] : 0;
    s[t] = v;
    __syncthreads();
    for (int off = 1; off < SCAN_T; off <<= 1) {
        int u = (t >= off) ? s[t - off] : 0;
        __syncthreads();
        s[t] += u;
        __syncthreads();
    }
    int incl = s[t];
    int base = bsum[blockIdx.x];
    if (i < nn) {
        row_ptr[i] = base + incl - v;
        if (i == nn - 1) row_ptr[nn] = base + incl;
    }
}

// atomic-free scatter into CSR slots (interleaved {src, w})
__global__ void k_scatter2(const int* __restrict__ src, const int* __restrict__ dst,
                           const float* __restrict__ w, const int* __restrict__ row_ptr,
                           const int* __restrict__ rank, Ent* __restrict__ csr, int ne) {
    int e = blockIdx.x * blockDim.x + threadIdx.x;
    if (e >= ne) return;
    int slot = row_ptr[dst[e]] + rank[e];
    Ent en; en.s = src[e]; en.nw = w[e];
    csr[slot] = en;
}

// weighted in-degree from CSR segments -> dinv (no atomics); 8 lanes per node
__global__ void k_degi(const int* __restrict__ row_ptr, const Ent* __restrict__ csr,
                       float* __restrict__ dinv, int nn) {
    int tid = blockIdx.x * blockDim.x + threadIdx.x;
    int n = tid >> 3, lane = tid & 7;
    if (n >= nn) return;
    int beg = row_ptr[n], end = row_ptr[n + 1];
    float s = 0.f;
    for (int e = beg + lane; e < end; e += 8) s += csr[e].nw;
    s += __shfl_xor(s, 1, 64);
    s += __shfl_xor(s, 2, 64);
    s += __shfl_xor(s, 4, 64);
    if (lane == 0) dinv[n] = s > 0.f ? rsqrtf(fmaxf(s, 1e-30f)) : 0.f;
}

// rewrite entry weight -> norm = dinv[src]*w*dinv[dst] in place; 8 lanes per node
__global__ void k_norm2(const int* __restrict__ row_ptr, Ent* __restrict__ csr,
                        const float* __restrict__ dinv, int nn) {
    int tid = blockIdx.x * blockDim.x + threadIdx.x;
    int n = tid >> 3, lane = tid & 7;
    if (n >= nn) return;
    int beg = row_ptr[n], end = row_ptr[n + 1];
    float dn = dinv[n];
    for (int e = beg + lane; e < end; e += 8) {
        Ent en = csr[e];
        csr[e].nw = dinv[en.s] * en.nw * dn;
    }
}

// ---------------- fused 4-way dense mm: t[k] = h @ W[k], k=0..3 ----------------
template <int FIN, int FOUT>
__global__ void k_mm4(const float* __restrict__ h, const float* __restrict__ W,
                      float* __restrict__ t, int nn) {  // t: [4][nn][FOUT]
    __shared__ float sW[4 * FIN * FOUT];
    for (int i = threadIdx.x; i < 4 * FIN * FOUT; i += blockDim.x) sW[i] = W[i];
    __syncthreads();
    int n = blockIdx.x * blockDim.x + threadIdx.x;
    if (n >= nn) return;
    float hr[FIN];
    const float4* hp = reinterpret_cast<const float4*>(h + (size_t)n * FIN);
#pragma unroll
    for (int f = 0; f < FIN / 4; ++f) {
        float4 v = hp[f];
        hr[4 * f + 0] = v.x; hr[4 * f + 1] = v.y;
        hr[4 * f + 2] = v.z; hr[4 * f + 3] = v.w;
    }
#pragma unroll
    for (int k = 0; k < 4; ++k) {
        float acc[FOUT];
#pragma unroll
        for (int j = 0; j < FOUT; ++j) acc[j] = 0.f;
#pragma unroll
        for (int i = 0; i < FIN; ++i) {
            float hv = hr[i];
            const float* wrow = &sW[(k * FIN + i) * FOUT];
#pragma unroll
            for (int j = 0; j < FOUT; ++j) acc[j] = fmaf(hv, wrow[j], acc[j]);
        }
        float4* op = reinterpret_cast<float4*>(t + ((size_t)k * nn + n) * FOUT);
#pragma unroll
        for (int j4 = 0; j4 < FOUT / 4; ++j4)
            op[j4] = make_float4(acc[4 * j4], acc[4 * j4 + 1], acc[4 * j4 + 2], acc[4 * j4 + 3]);
    }
}

// ---------------- pull propagate with fused add (+ optional bias/relu) ----------------
// hout = A*hin + add  [+ bias, relu]; F lanes per node, lane j owns feature j
template <int F, bool EPI>
__global__ void k_pull(const int* __restrict__ row_ptr, const Ent* __restrict__ csr,
                       const float* __restrict__ hin, const float* __restrict__ add,
                       const float* __restrict__ b, float* __restrict__ hout, int nn) {
    int g = blockIdx.x * (blockDim.x / F) + threadIdx.x / F;
    int lane = threadIdx.x & (F - 1);
    if (g >= nn) return;
    int beg = row_ptr[g], end = row_ptr[g + 1];
    float acc0 = 0.f, acc1 = 0.f;
    int e = beg;
    for (; e + 1 < end; e += 2) {
        Ent e0 = csr[e], e1 = csr[e + 1];
        acc0 = fmaf(hin[(size_t)e0.s * F + lane], e0.nw, acc0);
        acc1 = fmaf(hin[(size_t)e1.s * F + lane], e1.nw, acc1);
    }
    if (e < end) {
        Ent e0 = csr[e];
        acc0 = fmaf(hin[(size_t)e0.s * F + lane], e0.nw, acc0);
    }
    float r = acc0 + acc1 + add[(size_t)g * F + lane];
    if (EPI) r = fmaxf(r + b[lane], 0.f);
    hout[(size_t)g * F + lane] = r;
}

// ---------------- pooling + FC (batch is sorted -> contiguous segments) ----------------

__global__ void k_bounds(const int* __restrict__ batch, int* __restrict__ start, int nn) {
    int i = blockIdx.x * blockDim.x + threadIdx.x;
    if (i >= nn) return;
    int b = batch[i];
    int prev = (i == 0) ? -1 : batch[i - 1];
    for (int g = prev + 1; g <= b; ++g) start[g] = i;
    if (i == nn - 1) {
        for (int g = b + 1; g <= NG; ++g) start[g] = nn;
    }
}

// one block per graph: segmented max+sum reduction (no atomics) + fused FC
__global__ void k_pool2(const float* __restrict__ h, const int* __restrict__ start,
                        const float* __restrict__ Wfc, const float* __restrict__ bfc,
                        float* __restrict__ out) {
    int g = blockIdx.x;
    int beg = start[g], end = start[g + 1];
    int tid = threadIdx.x;
    int feat = tid & 15, grp = tid >> 4;  // 16 node-groups x 16 features
    float mx = 0.f, sm = 0.f;  // post-ReLU values are >= 0
    for (int n = beg + grp; n < end; n += 16) {
        float v = h[(size_t)n * 16 + feat];
        mx = fmaxf(mx, v);
        sm += v;
    }
    mx = fmaxf(mx, __shfl_xor(mx, 16, 64));
    sm += __shfl_xor(sm, 16, 64);
    mx = fmaxf(mx, __shfl_xor(mx, 32, 64));
    sm += __shfl_xor(sm, 32, 64);
    __shared__ float smx[4][16], ssm[4][16];
    int wave = tid >> 6;
    int lane = tid & 63;
    if (lane < 16) { smx[wave][feat] = mx; ssm[wave][feat] = sm; }
    __syncthreads();
    if (tid < 16) {
        float m = fmaxf(fmaxf(smx[0][tid], smx[1][tid]), fmaxf(smx[2][tid], smx[3][tid]));
        float s = ssm[0][tid] + ssm[1][tid] + ssm[2][tid] + ssm[3][tid];
        smx[0][tid] = m;
        ssm[0][tid] = (end > beg) ? s / (float)(end - beg) : 0.f;
    }
    __syncthreads();
    if (tid < 2) {
        float acc = bfc[tid];
#pragma unroll
        for (int i = 0; i < 16; ++i) acc += smx[0][i] * Wfc[i * 2 + tid];
#pragma unroll
        for (int i = 0; i < 16; ++i) acc += ssm[0][i] * Wfc[(16 + i) * 2 + tid];
        out[g * 2 + tid] = acc;
    }
}

// ---------------- launch ----------------

extern "C" void kernel_launch(void* const* d_in, const int* in_sizes, int n_in,
                              void* d_out, int out_size, void* d_ws, size_t ws_size,
                              hipStream_t stream) {
    const float* x    = (const float*)d_in[0];           // NN x 32
    const int*   eidx = (const int*)d_in[1];             // 2 x NE
    const int*   srcp = eidx;
    const int*   dstp = eidx + NE;
    const int*   batch= (const int*)d_in[2];             // NN
    const float* ew   = (const float*)d_in[3];           // NE
    const float* W1   = (const float*)d_in[4];           // 4 x 32 x 8
    const float* b1   = (const float*)d_in[5];           // 8
    const float* W2   = (const float*)d_in[6];           // 4 x 8 x 16
    const float* b2   = (const float*)d_in[7];           // 16
    const float* Wfc  = (const float*)d_in[8];           // 32 x 2
    const float* bfc  = (const float*)d_in[9];           // 2
    float* out = (float*)d_out;                          // NG x 2

    constexpr size_t NN8  = (size_t)NN * 8;
    constexpr size_t NN16 = (size_t)NN * 16;

    // workspace layout (4-byte units; csr kept 8B-aligned)
    float* dinv     = (float*)d_ws;              // NN
    int*   cnt      = (int*)(dinv + NN);         // NN
    int*   row_ptr  = cnt + NN;                  // NN + 4
    int*   rank     = row_ptr + NN + 4;          // NE
    Ent*   csr      = (Ent*)(rank + NE);         // NE entries (2*NE words)
    float* uni      = (float*)(csr + NE);        // union region: 8 * NN16 max
    float* h1       = uni + 5 * NN16;            // NN*8 (outside layer-2 live set)
    int*   gstart   = (int*)(h1 + NN8);          // NG+1
    int*   bsum     = gstart + NG + 4;           // SCAN_B

    // layer-1 aliases inside union: T = 4 x NN8 (= 2*NN16), P, P2
    float* T  = uni;                 // t0..t3, each NN8
    float* P  = uni + 2 * NN16;      // NN8
    float* P2 = P + NN8;             // NN8
    // layer-2 aliases: U = 4 x NN16, q, q2/out2 reuse dead u-slots
    float* U    = uni;               // u0..u3, each NN16
    float* q    = uni + 4 * NN16;    // NN16
    float* q2   = U + 3 * NN16;      // u3 slot (dead after hop 1)
    float* out2 = U + 2 * NN16;      // u2 slot (dead after hop 1)

    const int BLK = 256;
    const int gE = (NE + BLK - 1) / BLK;
    const int gN = (NN + BLK - 1) / BLK;
    const int gP8  = (NN + (BLK / 8) - 1) / (BLK / 8);
    const int gP16 = (NN + (BLK / 16) - 1) / (BLK / 16);
    const int gN8  = (NN * 8 + BLK - 1) / BLK;

    // ---- CSR build + gcn_norm (single atomic pass) ----
    hipMemsetAsync(cnt, 0, (size_t)NN * sizeof(int), stream);
    k_rank<<<gE, BLK, 0, stream>>>(dstp, cnt, rank, NE);
    k_scan1<<<SCAN_B, SCAN_T, 0, stream>>>(cnt, bsum, NN);
    k_scan2<<<1, 512, 0, stream>>>(bsum, SCAN_B);
    k_scan3<<<SCAN_B, SCAN_T, 0, stream>>>(cnt, bsum, row_ptr, NN);
    k_scatter2<<<gE, BLK, 0, stream>>>(srcp, dstp, ew, row_ptr, rank, csr, NE);
    k_degi<<<gN8, BLK, 0, stream>>>(row_ptr, csr, dinv, NN);
    k_norm2<<<gN8, BLK, 0, stream>>>(row_ptr, csr, dinv, NN);
    k_bounds<<<gN, BLK, 0, stream>>>(batch, gstart, NN);

    // ---- layer 1 (Horner): propagate at F=8 ----
    // t_k = x @ W1[k]; s1 = A t3 + t2; s2 = A s1 + t1; h1 = relu(A s2 + t0 + b1)
    k_mm4<32, 8><<<gN, BLK, 0, stream>>>(x, W1, T, NN);
    k_pull<8, false><<<gP8, BLK, 0, stream>>>(row_ptr, csr, T + 3 * NN8, T + 2 * NN8, nullptr, P, NN);
    k_pull<8, false><<<gP8, BLK, 0, stream>>>(row_ptr, csr, P, T + 1 * NN8, nullptr, P2, NN);
    k_pull<8, true ><<<gP8, BLK, 0, stream>>>(row_ptr, csr, P2, T, b1, h1, NN);

    // ---- layer 2 (Horner): propagate at F=16 ----
    k_mm4<8, 16><<<gN, BLK, 0, stream>>>(h1, W2, U, NN);
    k_pull<16, false><<<gP16, BLK, 0, stream>>>(row_ptr, csr, U + 3 * NN16, U + 2 * NN16, nullptr, q, NN);
    k_pull<16, false><<<gP16, BLK, 0, stream>>>(row_ptr, csr, q, U + 1 * NN16, nullptr, q2, NN);
    k_pull<16, true ><<<gP16, BLK, 0, stream>>>(row_ptr, csr, q2, U, b2, out2, NN);

    // ---- pooling + fused FC (no atomics) ----
    k_pool2<<<NG, 256, 0, stream>>>(out2, gstart, Wfc, bfc, out);
}

// Round 7
// 309.800 us; speedup vs baseline: 34.2989x; 1.1691x over previous
//
#include <hip/hip_runtime.h>

// Problem constants (match reference setup_inputs)
constexpr int NN = 100000;   // nodes
constexpr int NE = 1600000;  // edges
constexpr int NG = 128;      // graphs

constexpr int SCAN_T = 256;
constexpr int SCAN_B = (NN + SCAN_T - 1) / SCAN_T;  // 391

// interleaved CSR entry: src index + raw edge weight (norm folded into pulls)
struct __align__(8) Ent { int s; float nw; };

// ---------------- CSR build ----------------

// the only atomic pass: in-degree count + per-edge rank (4 edges/thread)
__global__ void k_rank(const int4* __restrict__ dst4, int* __restrict__ cnt,
                       ushort4* __restrict__ rank4, int ne4) {
    int i = blockIdx.x * blockDim.x + threadIdx.x;
    if (i >= ne4) return;
    int4 d = dst4[i];
    ushort4 r;
    r.x = (ushort)atomicAdd(&cnt[d.x], 1);
    r.y = (ushort)atomicAdd(&cnt[d.y], 1);
    r.z = (ushort)atomicAdd(&cnt[d.z], 1);
    r.w = (ushort)atomicAdd(&cnt[d.w], 1);
    rank4[i] = r;
}

// ---- multi-block exclusive scan of PADDED counts -> row_ptr (segments even) ----

__global__ void k_scan1(const int* __restrict__ cnt, int* __restrict__ bsum, int nn) {
    __shared__ int s[SCAN_T];
    int i = blockIdx.x * SCAN_T + threadIdx.x;
    s[threadIdx.x] = (i < nn) ? ((cnt[i] + 1) & ~1) : 0;
    __syncthreads();
    for (int off = SCAN_T / 2; off > 0; off >>= 1) {
        if (threadIdx.x < off) s[threadIdx.x] += s[threadIdx.x + off];
        __syncthreads();
    }
    if (threadIdx.x == 0) bsum[blockIdx.x] = s[0];
}

__global__ void k_scan2(int* __restrict__ bsum, int nb) {
    __shared__ int s[512];
    int t = threadIdx.x;
    s[t] = (t < nb) ? bsum[t] : 0;
    __syncthreads();
    for (int off = 1; off < 512; off <<= 1) {
        int v = (t >= off) ? s[t - off] : 0;
        __syncthreads();
        s[t] += v;
        __syncthreads();
    }
    if (t < nb) bsum[t] = (t > 0) ? s[t - 1] : 0;
}

__global__ void k_scan3(const int* __restrict__ cnt, const int* __restrict__ bsum,
                        int* __restrict__ row_ptr, int nn) {
    __shared__ int s[SCAN_T];
    int t = threadIdx.x;
    int i = blockIdx.x * SCAN_T + t;
    int v = (i < nn) ? ((cnt[i] + 1) & ~1) : 0;
    s[t] = v;
    __syncthreads();
    for (int off = 1; off < SCAN_T; off <<= 1) {
        int u = (t >= off) ? s[t - off] : 0;
        __syncthreads();
        s[t] += u;
        __syncthreads();
    }
    int incl = s[t];
    int base = bsum[blockIdx.x];
    if (i < nn) {
        row_ptr[i] = base + incl - v;
        if (i == nn - 1) row_ptr[nn] = base + incl;
    }
}

// atomic-free scatter into CSR slots (4 edges/thread)
__global__ void k_scatter2(const int4* __restrict__ src4, const int4* __restrict__ dst4,
                           const float4* __restrict__ w4, const int* __restrict__ row_ptr,
                           const ushort4* __restrict__ rank4, Ent* __restrict__ csr, int ne4) {
    int i = blockIdx.x * blockDim.x + threadIdx.x;
    if (i >= ne4) return;
    int4 s = src4[i]; int4 d = dst4[i]; float4 w = w4[i]; ushort4 r = rank4[i];
    Ent e0; e0.s = s.x; e0.nw = w.x; csr[row_ptr[d.x] + r.x] = e0;
    Ent e1; e1.s = s.y; e1.nw = w.y; csr[row_ptr[d.y] + r.y] = e1;
    Ent e2; e2.s = s.z; e2.nw = w.z; csr[row_ptr[d.z] + r.z] = e2;
    Ent e3; e3.s = s.w; e3.nw = w.w; csr[row_ptr[d.w] + r.w] = e3;
}

// fill the one zero pad entry for odd-degree nodes (exact no-op in all sums)
__global__ void k_pad(const int* __restrict__ cnt, const int* __restrict__ row_ptr,
                      Ent* __restrict__ csr, int nn) {
    int n = blockIdx.x * blockDim.x + threadIdx.x;
    if (n < nn && (cnt[n] & 1)) {
        Ent z; z.s = 0; z.nw = 0.f;
        csr[row_ptr[n] + cnt[n]] = z;
    }
}

// weighted in-degree from CSR segments -> dinv; 8 lanes per node, float4 loads
__global__ void k_degi(const int* __restrict__ row_ptr, const float4* __restrict__ csr4,
                       float* __restrict__ dinv, int nn) {
    int tid = blockIdx.x * blockDim.x + threadIdx.x;
    int n = tid >> 3, lane = tid & 7;
    if (n >= nn) return;
    int beg = row_ptr[n] >> 1, end = row_ptr[n + 1] >> 1;  // pair units
    float s = 0.f;
    for (int p = beg + lane; p < end; p += 8) {
        float4 a = csr4[p];
        s += a.y + a.w;
    }
    s += __shfl_xor(s, 1, 64);
    s += __shfl_xor(s, 2, 64);
    s += __shfl_xor(s, 4, 64);
    if (lane == 0) dinv[n] = s > 0.f ? rsqrtf(fmaxf(s, 1e-30f)) : 0.f;
}

// ---------------- fused 4-way dense mm: t[k] = h @ W[k]; k==3 output pre-scaled by dinv ----
template <int FIN, int FOUT>
__global__ void k_mm4(const float* __restrict__ h, const float* __restrict__ W,
                      const float* __restrict__ dinv, float* __restrict__ t, int nn) {
    __shared__ float sW[4 * FIN * FOUT];
    for (int i = threadIdx.x; i < 4 * FIN * FOUT; i += blockDim.x) sW[i] = W[i];
    __syncthreads();
    int n = blockIdx.x * blockDim.x + threadIdx.x;
    if (n >= nn) return;
    float hr[FIN];
    const float4* hp = reinterpret_cast<const float4*>(h + (size_t)n * FIN);
#pragma unroll
    for (int f = 0; f < FIN / 4; ++f) {
        float4 v = hp[f];
        hr[4 * f + 0] = v.x; hr[4 * f + 1] = v.y;
        hr[4 * f + 2] = v.z; hr[4 * f + 3] = v.w;
    }
    float dv = dinv[n];
#pragma unroll
    for (int k = 0; k < 4; ++k) {
        float acc[FOUT];
#pragma unroll
        for (int j = 0; j < FOUT; ++j) acc[j] = 0.f;
#pragma unroll
        for (int i = 0; i < FIN; ++i) {
            float hv = hr[i];
            const float* wrow = &sW[(k * FIN + i) * FOUT];
#pragma unroll
            for (int j = 0; j < FOUT; ++j) acc[j] = fmaf(hv, wrow[j], acc[j]);
        }
        if (k == 3) {
#pragma unroll
            for (int j = 0; j < FOUT; ++j) acc[j] *= dv;
        }
        float4* op = reinterpret_cast<float4*>(t + ((size_t)k * nn + n) * FOUT);
#pragma unroll
        for (int j4 = 0; j4 < FOUT / 4; ++j4)
            op[j4] = make_float4(acc[4 * j4], acc[4 * j4 + 1], acc[4 * j4 + 2], acc[4 * j4 + 3]);
    }
}

// ---------------- pull propagate (dinv folded; fused add / bias+relu) ----------------
// MID:   hout = dinv[d] * (dinv[d]*Sum + add[d])     (pre-scaled for next hop)
// FINAL: hout = relu(dinv[d]*Sum + add[d] + b)
template <int F, bool FINAL>
__global__ void k_pull(const int* __restrict__ row_ptr, const float4* __restrict__ csr4,
                       const float* __restrict__ dinv,
                       const float* __restrict__ hin, const float* __restrict__ add,
                       const float* __restrict__ b, float* __restrict__ hout, int nn) {
    int g = blockIdx.x * (blockDim.x / F) + threadIdx.x / F;
    int lane = threadIdx.x & (F - 1);
    if (g >= nn) return;
    int p = row_ptr[g] >> 1, end = row_ptr[g + 1] >> 1;  // pair units (segments even)
    float acc0 = 0.f, acc1 = 0.f, acc2 = 0.f, acc3 = 0.f;
    for (; p + 2 <= end; p += 2) {
        float4 a = csr4[p], c = csr4[p + 1];
        acc0 = fmaf(hin[(size_t)__float_as_int(a.x) * F + lane], a.y, acc0);
        acc1 = fmaf(hin[(size_t)__float_as_int(a.z) * F + lane], a.w, acc1);
        acc2 = fmaf(hin[(size_t)__float_as_int(c.x) * F + lane], c.y, acc2);
        acc3 = fmaf(hin[(size_t)__float_as_int(c.z) * F + lane], c.w, acc3);
    }
    if (p < end) {
        float4 a = csr4[p];
        acc0 = fmaf(hin[(size_t)__float_as_int(a.x) * F + lane], a.y, acc0);
        acc1 = fmaf(hin[(size_t)__float_as_int(a.z) * F + lane], a.w, acc1);
    }
    float acc = (acc0 + acc1) + (acc2 + acc3);
    float dv = dinv[g];
    float r;
    if (FINAL) r = fmaxf(dv * acc + add[(size_t)g * F + lane] + b[lane], 0.f);
    else       r = dv * (dv * acc + add[(size_t)g * F + lane]);
    hout[(size_t)g * F + lane] = r;
}

// ---------------- pooling + FC (batch is sorted -> contiguous segments) ----------------

__global__ void k_bounds(const int* __restrict__ batch, int* __restrict__ start, int nn) {
    int i = blockIdx.x * blockDim.x + threadIdx.x;
    if (i >= nn) return;
    int b = batch[i];
    int prev = (i == 0) ? -1 : batch[i - 1];
    for (int g = prev + 1; g <= b; ++g) start[g] = i;
    if (i == nn - 1) {
        for (int g = b + 1; g <= NG; ++g) start[g] = nn;
    }
}

// one block per graph: segmented max+sum reduction (no atomics) + fused FC
__global__ void k_pool2(const float* __restrict__ h, const int* __restrict__ start,
                        const float* __restrict__ Wfc, const float* __restrict__ bfc,
                        float* __restrict__ out) {
    int g = blockIdx.x;
    int beg = start[g], end = start[g + 1];
    int tid = threadIdx.x;
    int feat = tid & 15, grp = tid >> 4;  // 16 node-groups x 16 features
    float mx = 0.f, sm = 0.f;  // post-ReLU values are >= 0
    for (int n = beg + grp; n < end; n += 16) {
        float v = h[(size_t)n * 16 + feat];
        mx = fmaxf(mx, v);
        sm += v;
    }
    mx = fmaxf(mx, __shfl_xor(mx, 16, 64));
    sm += __shfl_xor(sm, 16, 64);
    mx = fmaxf(mx, __shfl_xor(mx, 32, 64));
    sm += __shfl_xor(sm, 32, 64);
    __shared__ float smx[4][16], ssm[4][16];
    int wave = tid >> 6;
    int lane = tid & 63;
    if (lane < 16) { smx[wave][feat] = mx; ssm[wave][feat] = sm; }
    __syncthreads();
    if (tid < 16) {
        float m = fmaxf(fmaxf(smx[0][tid], smx[1][tid]), fmaxf(smx[2][tid], smx[3][tid]));
        float s = ssm[0][tid] + ssm[1][tid] + ssm[2][tid] + ssm[3][tid];
        smx[0][tid] = m;
        ssm[0][tid] = (end > beg) ? s / (float)(end - beg) : 0.f;
    }
    __syncthreads();
    if (tid < 2) {
        float acc = bfc[tid];
#pragma unroll
        for (int i = 0; i < 16; ++i) acc += smx[0][i] * Wfc[i * 2 + tid];
#pragma unroll
        for (int i = 0; i < 16; ++i) acc += ssm[0][i] * Wfc[(16 + i) * 2 + tid];
        out[g * 2 + tid] = acc;
    }
}

// ---------------- launch ----------------

extern "C" void kernel_launch(void* const* d_in, const int* in_sizes, int n_in,
                              void* d_out, int out_size, void* d_ws, size_t ws_size,
                              hipStream_t stream) {
    const float* x    = (const float*)d_in[0];           // NN x 32
    const int*   eidx = (const int*)d_in[1];             // 2 x NE
    const int*   srcp = eidx;
    const int*   dstp = eidx + NE;
    const int*   batch= (const int*)d_in[2];             // NN
    const float* ew   = (const float*)d_in[3];           // NE
    const float* W1   = (const float*)d_in[4];           // 4 x 32 x 8
    const float* b1   = (const float*)d_in[5];           // 8
    const float* W2   = (const float*)d_in[6];           // 4 x 8 x 16
    const float* b2   = (const float*)d_in[7];           // 16
    const float* Wfc  = (const float*)d_in[8];           // 32 x 2
    const float* bfc  = (const float*)d_in[9];           // 2
    float* out = (float*)d_out;                          // NG x 2

    constexpr size_t NN8  = (size_t)NN * 8;
    constexpr size_t NN16 = (size_t)NN * 16;

    // workspace layout (4-byte units; csr & uni kept 16B-aligned)
    float*  dinv    = (float*)d_ws;               // NN
    int*    cnt     = (int*)(dinv + NN);          // NN
    int*    row_ptr = cnt + NN;                   // NN + 4
    ushort* rank    = (ushort*)(row_ptr + NN + 4);// NE ushorts (NE/2 ints = 800000)
    Ent*    csr     = (Ent*)((int*)(void*)rank + NE / 2);  // NE+NN entries
    float*  uni     = (float*)(csr + NE + NN);    // union region
    float*  h1      = uni + 5 * NN16;             // NN*8
    int*    gstart  = (int*)(h1 + NN8);           // NG+1
    int*    bsum    = gstart + NG + 4;            // SCAN_B

    // layer-1 aliases: T = 4 x NN8, P, P2
    float* T  = uni;
    float* P  = uni + 2 * NN16;
    float* P2 = P + NN8;
    // layer-2 aliases: U = 4 x NN16, q, q2/out2 reuse dead u-slots
    float* U    = uni;
    float* q    = uni + 4 * NN16;
    float* q2   = U + 3 * NN16;   // u3 slot (dead after hop 1)
    float* out2 = U + 2 * NN16;   // u2 slot (dead after hop 1)

    const float4* csr4 = (const float4*)csr;

    const int BLK = 256;
    const int NE4 = NE / 4;
    const int gE4 = (NE4 + BLK - 1) / BLK;
    const int gN  = (NN + BLK - 1) / BLK;
    const int gP8  = (NN + (BLK / 8) - 1) / (BLK / 8);
    const int gP16 = (NN + (BLK / 16) - 1) / (BLK / 16);
    const int gN8  = (NN * 8 + BLK - 1) / BLK;

    // ---- CSR build (single atomic pass, raw weights; norm folded into pulls) ----
    hipMemsetAsync(cnt, 0, (size_t)NN * sizeof(int), stream);
    k_rank<<<gE4, BLK, 0, stream>>>((const int4*)dstp, cnt, (ushort4*)rank, NE4);
    k_scan1<<<SCAN_B, SCAN_T, 0, stream>>>(cnt, bsum, NN);
    k_scan2<<<1, 512, 0, stream>>>(bsum, SCAN_B);
    k_scan3<<<SCAN_B, SCAN_T, 0, stream>>>(cnt, bsum, row_ptr, NN);
    k_scatter2<<<gE4, BLK, 0, stream>>>((const int4*)srcp, (const int4*)dstp,
                                        (const float4*)ew, row_ptr, (const ushort4*)rank,
                                        csr, NE4);
    k_pad<<<gN, BLK, 0, stream>>>(cnt, row_ptr, csr, NN);
    k_degi<<<gN8, BLK, 0, stream>>>(row_ptr, csr4, dinv, NN);
    k_bounds<<<gN, BLK, 0, stream>>>(batch, gstart, NN);

    // ---- layer 1 (Horner, dinv-folded): propagate at F=8 ----
    k_mm4<32, 8><<<gN, BLK, 0, stream>>>(x, W1, dinv, T, NN);
    k_pull<8, false><<<gP8, BLK, 0, stream>>>(row_ptr, csr4, dinv, T + 3 * NN8, T + 2 * NN8, nullptr, P, NN);
    k_pull<8, false><<<gP8, BLK, 0, stream>>>(row_ptr, csr4, dinv, P, T + 1 * NN8, nullptr, P2, NN);
    k_pull<8, true ><<<gP8, BLK, 0, stream>>>(row_ptr, csr4, dinv, P2, T, b1, h1, NN);

    // ---- layer 2 (Horner, dinv-folded): propagate at F=16 ----
    k_mm4<8, 16><<<gN, BLK, 0, stream>>>(h1, W2, dinv, U, NN);
    k_pull<16, false><<<gP16, BLK, 0, stream>>>(row_ptr, csr4, dinv, U + 3 * NN16, U + 2 * NN16, nullptr, q, NN);
    k_pull<16, false><<<gP16, BLK, 0, stream>>>(row_ptr, csr4, dinv, q, U + 1 * NN16, nullptr, q2, NN);
    k_pull<16, true ><<<gP16, BLK, 0, stream>>>(row_ptr, csr4, dinv, q2, U, b2, out2, NN);

    // ---- pooling + fused FC (no atomics) ----
    k_pool2<<<NG, 256, 0, stream>>>(out2, gstart, Wfc, bfc, out);
}